// Round 4
// baseline (304.718 us; speedup 1.0000x reference)
//
#include <hip/hip_runtime.h>
#include <hip/hip_bf16.h>

typedef unsigned short u16;
typedef __bf16 bf16x8 __attribute__((ext_vector_type(8)));
typedef float f32x4 __attribute__((ext_vector_type(4)));

#define B_ 2
#define L_ 2048
#define D_ 128
#define KLAY 3
#define NR 16
#define NATOM 118
#define NBLK 256
#define DD (D_ * D_)
#define XTN (L_ * D_)  // elems per batch in XTs

static __device__ __forceinline__ u16 f2bf(float f) {
    union { float f; unsigned u; } v; v.f = f;
    unsigned r = v.u + 0x7FFFu + ((v.u >> 16) & 1u);
    return (u16)(r >> 16);
}
static __device__ __forceinline__ bf16x8 ld_bf8(const u16* p) {
    return *(const bf16x8*)p;
}

// Device-wide barrier: bar[0]=arrive count, bar[1]=epoch. Requires all NBLK
// blocks co-resident (grid=256=CU count, 1 block/CU capacity verified).
__device__ __forceinline__ void gridbar(unsigned* bar) {
    __syncthreads();
    __threadfence();
    if (threadIdx.x == 0) {
        unsigned e = __hip_atomic_load(bar + 1, __ATOMIC_RELAXED, __HIP_MEMORY_SCOPE_AGENT);
        unsigned old = __hip_atomic_fetch_add(bar, 1u, __ATOMIC_ACQ_REL, __HIP_MEMORY_SCOPE_AGENT);
        if (old == NBLK - 1) {
            __hip_atomic_store(bar, 0u, __ATOMIC_RELAXED, __HIP_MEMORY_SCOPE_AGENT);
            __hip_atomic_store(bar + 1, e + 1u, __ATOMIC_RELEASE, __HIP_MEMORY_SCOPE_AGENT);
        } else {
            while (__hip_atomic_load(bar + 1, __ATOMIC_ACQUIRE, __HIP_MEMORY_SCOPE_AGENT) == e)
                __builtin_amdgcn_s_sleep(2);
        }
    }
    __syncthreads();
}

// ---------------- geo: weight-prep + pairwise + RBF + encoder + layer-0 S/X ----------------
__global__ __launch_bounds__(1024) void geo_kernel(
    const float* coords, const int* Z, const float* atom_emb,
    const float* gamma_p, const float* centers, const float* rbf_w,
    const float* rbf_b, const float* out_w, const float* out_b,
    const float* self_w, const float* self_b, const float* msg_w,
    const float* msg_b, const float* upd_w,
    u16* W16, u16* atom16, u16* outwT, u16* selfT, u16* msgT, u16* updT,
    u16* S_a, u16* XTs_a, unsigned* bar) {
    int bt = blockIdx.x;
    int gi0 = bt * 16;
    int b = gi0 >> 11;
    int il0 = gi0 & (L_ - 1);
    int tid = threadIdx.x;

    __shared__ float cen[NR];
    __shared__ float rbf_lds[16][NR];
    __shared__ __align__(16) u16 hgeo[16][136];
    __shared__ __align__(16) u16 h_lds[16][136];

    if (tid < NR) cen[tid] = centers[tid];

    // ---- Phase 0: weight conversion, grid-strided (consumed after gridbar) ----
    {
        const int T0 = NATOM * D_;
        const int T1 = D_ * 2 * D_;
        const int T2 = KLAY * DD;
        const int T3 = KLAY * DD;
        const int T4 = KLAY * 2 * DD;
        int total = T0 + T1 + T2 + T3 + T4;
        for (int t = bt * 1024 + tid; t < total; t += NBLK * 1024) {
            int u = t;
            if (u < T0) { atom16[u] = f2bf(atom_emb[u]); continue; }
            u -= T0;
            if (u < T1) {
                int n = u / (2 * D_), k = u % (2 * D_);
                outwT[u] = f2bf(out_w[k * D_ + n]);
                continue;
            }
            u -= T1;
            if (u < T2) {
                int kk = u / DD, v = u % DD;
                int n = v / D_, k = v % D_;
                selfT[u] = f2bf(self_w[kk * DD + k * D_ + n]);
                continue;
            }
            u -= T2;
            if (u < T3) {
                int kk = u / DD, v = u % DD;
                int n = v / D_, k = v % D_;
                msgT[u] = f2bf(msg_w[kk * DD + k * D_ + n]);
                continue;
            }
            u -= T3;
            {
                int kk = u / (2 * DD), v = u % (2 * DD);
                int n = v / (2 * D_), k = v % (2 * D_);
                updT[u] = f2bf(upd_w[kk * 2 * DD + k * D_ + n]);
            }
        }
    }
    __syncthreads();  // cen visible

    // ---- Phase A: pairwise for own 16 rows (wave = 1 row, 32 j's per lane) ----
    {
        int row = tid >> 6, s = tid & 63;
        int gi = gi0 + row;
        float gamma = gamma_p[0];
        float cx = coords[gi * 3 + 0];
        float cy = coords[gi * 3 + 1];
        float cz = coords[gi * 3 + 2];
        const float* cb = coords + (size_t)b * L_ * 3;
        u16* wrow = W16 + (size_t)gi * L_;
        float acc[NR];
#pragma unroll
        for (int r = 0; r < NR; r++) acc[r] = 0.f;
        for (int m = 0; m < 32; m++) {
            int j = s + 64 * m;
            float dx = cx - cb[j * 3 + 0];
            float dy = cy - cb[j * 3 + 1];
            float dz = cz - cb[j * 3 + 2];
            float sq = dx * dx + dy * dy + dz * dz;
            float d = sq > 0.f ? sqrtf(sq) : 0.f;
            wrow[j] = f2bf(__expf(-d));
#pragma unroll
            for (int r = 0; r < NR; r++) {
                float t = d - cen[r];
                acc[r] += __expf(-gamma * t * t);
            }
        }
#pragma unroll
        for (int off = 32; off > 0; off >>= 1)
#pragma unroll
            for (int r = 0; r < NR; r++) acc[r] += __shfl_xor(acc[r], off);
        if (s == 0) {
#pragma unroll
            for (int r = 0; r < NR; r++) rbf_lds[row][r] = acc[r] * (1.0f / L_);
        }
    }

    gridbar(bar);  // weights (phase 0) + rbf_lds now visible

    // ---- Phase B: hgeo = rbf_local @ rbf_w + rbf_b ----
    for (int e = tid; e < 16 * D_; e += 1024) {
        int rr = e >> 7, d = e & 127;
        float sacc = rbf_b[d];
#pragma unroll
        for (int r = 0; r < NR; r++) sacc += rbf_lds[rr][r] * rbf_w[r * D_ + d];
        hgeo[rr][d] = f2bf(sacc);
    }
    __syncthreads();

    int w = tid >> 6, lane = tid & 63;
    int rowf = lane & 15, kg = lane >> 4;
    f32x4 z = {0.f, 0.f, 0.f, 0.f};

    // ---- Phase C: h = cat(atom_emb[Z], hgeo) @ out_w + out_b (waves 0-7) ----
    if (w < 8) {
        f32x4 a1 = z;
        int za = Z[gi0 + rowf];
        int cl = w * 16 + rowf;
        for (int ks = 0; ks < 8; ks++) {
            int k0 = ks * 32 + kg * 8;
            bf16x8 av = (k0 < 128) ? ld_bf8(atom16 + za * D_ + k0)
                                   : ld_bf8(&hgeo[rowf][k0 - 128]);
            a1 = __builtin_amdgcn_mfma_f32_16x16x32_bf16(
                av, ld_bf8(outwT + cl * 2 * D_ + k0), a1, 0, 0, 0);
        }
        float bias = out_b[cl];
#pragma unroll
        for (int r = 0; r < 4; r++) h_lds[kg * 4 + r][cl] = f2bf(a1[r] + bias);
    }
    __syncthreads();

    // ---- Phase D: S0 (waves 0-7) and X0^T (waves 8-15) ----
    {
        int cl = (w & 7) * 16 + rowf;
        const u16* wT = (w < 8) ? (selfT + cl * D_) : (msgT + cl * D_);
        f32x4 a3 = z;
#pragma unroll
        for (int ks = 0; ks < 4; ks++) {
            int k0 = ks * 32 + kg * 8;
            a3 = __builtin_amdgcn_mfma_f32_16x16x32_bf16(
                ld_bf8(&h_lds[rowf][k0]), ld_bf8(wT + k0), a3, 0, 0, 0);
        }
        if (w < 8) {
            float bias = self_b[cl];
#pragma unroll
            for (int r = 0; r < 4; r++)
                S_a[(size_t)(gi0 + kg * 4 + r) * D_ + cl] = f2bf(a3[r] + bias);
        } else {
            float bias = msg_b[cl];
            int jg = il0 + kg * 4;
#pragma unroll
            for (int r = 0; r < 4; r++) {
                int jj = jg + r;
                XTs_a[(size_t)b * XTN + (jj >> 5) * (32 * D_) + cl * 32 + (jj & 31)] =
                    f2bf(a3[r] + bias);
            }
        }
    }
}

// ---------------- mp3: all three MP layers, persistent, 2 grid barriers ----------------
__global__ __launch_bounds__(512, 2) void mp3_kernel(
    const u16* W16, const u16* selfT, const u16* msgT, const u16* updT,
    const float* self_b, const float* msg_b, const float* upd_b,
    u16* S_a, u16* XTs_a, u16* S_b, u16* XTs_b,
    float* out_f32, unsigned* bar) {
    int bt = blockIdx.x;
    int gi0 = bt * 16;
    int b = gi0 >> 11;
    int il0 = gi0 & (L_ - 1);
    int tid = threadIdx.x;
    int w = tid >> 6, lane = tid & 63;
    int rowf = lane & 15, kg = lane >> 4;

    __shared__ __align__(16) float red[4][16][128];  // 32 KB
    u16* msg_lds = (u16*)&red[0][0][0];              // [16][136] bf16 alias
    u16* h_lds = (u16*)&red[1][0][0];                // [16][136] bf16 alias

    f32x4 z = {0.f, 0.f, 0.f, 0.f};
    const u16* Sin = S_a;
    const u16* XTin = XTs_a;
    u16* Sout = S_b;
    u16* XTout = XTs_b;

    for (int k = 0; k < KLAY; k++) {
        // ---- msg GEMM: wave w owns j-chunk [w*256, w*256+256) ----
        f32x4 acc[8] = {z, z, z, z, z, z, z, z};
        const u16* wbase = W16 + (size_t)(gi0 + rowf) * L_ + w * 256 + kg * 8;
        const u16* xbase = XTin + (size_t)b * XTN + (w * 8) * (32 * D_) + rowf * 32 + kg * 8;
#pragma unroll 2
        for (int s = 0; s < 8; s++) {
            bf16x8 a = ld_bf8(wbase + s * 32);
#pragma unroll
            for (int n = 0; n < 8; n++) {
                bf16x8 bb = ld_bf8(xbase + s * (32 * D_) + n * (16 * 32));
                acc[n] = __builtin_amdgcn_mfma_f32_16x16x32_bf16(a, bb, acc[n], 0, 0, 0);
            }
        }
        // ---- LDS tree reduce across 8 waves ----
        auto stash = [&](int slot) {
#pragma unroll
            for (int n = 0; n < 8; n++)
#pragma unroll
                for (int r = 0; r < 4; r++) {
                    int row = kg * 4 + r, col = n * 16 + rowf;
                    red[slot][row][(col + 4 * row) & 127] = acc[n][r];
                }
        };
        auto grab = [&](int slot) {
#pragma unroll
            for (int n = 0; n < 8; n++)
#pragma unroll
                for (int r = 0; r < 4; r++) {
                    int row = kg * 4 + r, col = n * 16 + rowf;
                    acc[n][r] += red[slot][row][(col + 4 * row) & 127];
                }
        };
        if (w >= 4) stash(w - 4);
        __syncthreads();
        if (w < 4) grab(w);
        if (w == 2 || w == 3) stash(w);
        __syncthreads();
        if (w < 2) grab(w + 2);
        if (w == 1) stash(3);
        __syncthreads();
        if (w == 0) {
            grab(3);
#pragma unroll
            for (int n = 0; n < 8; n++)
#pragma unroll
                for (int r = 0; r < 4; r++)
                    msg_lds[(kg * 4 + r) * 136 + n * 16 + rowf] = f2bf(acc[n][r]);
        }
        __syncthreads();
        // ---- epilogue: h' = S@U_top + msg@U_bot + bias ----
        const u16* updk = updT + k * 2 * DD;
        f32x4 acc2 = z;
        int cl = w * 16 + rowf;
        for (int ks = 0; ks < 8; ks++) {
            int k0 = ks * 32 + kg * 8;
            bf16x8 av = (ks < 4) ? ld_bf8(Sin + (size_t)(gi0 + rowf) * D_ + k0)
                                 : ld_bf8(msg_lds + rowf * 136 + (k0 - 128));
            acc2 = __builtin_amdgcn_mfma_f32_16x16x32_bf16(
                av, ld_bf8(updk + cl * 2 * D_ + k0), acc2, 0, 0, 0);
        }
        float bias = upd_b[k * D_ + cl];
        if (k == KLAY - 1) {
#pragma unroll
            for (int r = 0; r < 4; r++)
                out_f32[(size_t)(gi0 + kg * 4 + r) * D_ + cl] = acc2[r] + bias;
        } else {
#pragma unroll
            for (int r = 0; r < 4; r++)
                h_lds[(kg * 4 + r) * 136 + cl] = f2bf(acc2[r] + bias);
            __syncthreads();
            // ---- next-layer S/X (row-local) ----
            const u16* sT = selfT + (k + 1) * DD;
            const u16* mT = msgT + (k + 1) * DD;
            f32x4 a30 = z, a31 = z;
#pragma unroll
            for (int ks = 0; ks < 4; ks++) {
                int k0 = ks * 32 + kg * 8;
                bf16x8 av = ld_bf8(h_lds + rowf * 136 + k0);
                a30 = __builtin_amdgcn_mfma_f32_16x16x32_bf16(
                    av, ld_bf8(sT + cl * D_ + k0), a30, 0, 0, 0);
                a31 = __builtin_amdgcn_mfma_f32_16x16x32_bf16(
                    av, ld_bf8(mT + cl * D_ + k0), a31, 0, 0, 0);
            }
            float bs = self_b[(k + 1) * D_ + cl];
            float bm = msg_b[(k + 1) * D_ + cl];
#pragma unroll
            for (int r = 0; r < 4; r++)
                Sout[(size_t)(gi0 + kg * 4 + r) * D_ + cl] = f2bf(a30[r] + bs);
            int jg = il0 + kg * 4;
#pragma unroll
            for (int r = 0; r < 4; r++) {
                int jj = jg + r;
                XTout[(size_t)b * XTN + (jj >> 5) * (32 * D_) + cl * 32 + (jj & 31)] =
                    f2bf(a31[r] + bm);
            }
            gridbar(bar);
            const u16* t1 = Sin; Sin = Sout; Sout = (u16*)t1;
            const u16* t2 = XTin; XTin = XTout; XTout = (u16*)t2;
        }
    }
}

extern "C" void kernel_launch(void* const* d_in, const int* in_sizes, int n_in,
                              void* d_out, int out_size, void* d_ws, size_t ws_size,
                              hipStream_t stream) {
    const float* coords = (const float*)d_in[0];
    const int* Z = (const int*)d_in[1];
    const float* atom_emb = (const float*)d_in[2];
    const float* gamma = (const float*)d_in[3];
    const float* centers = (const float*)d_in[4];
    const float* rbf_w = (const float*)d_in[5];
    const float* rbf_b = (const float*)d_in[6];
    const float* out_w = (const float*)d_in[7];
    const float* out_b = (const float*)d_in[8];
    const float* self_w = (const float*)d_in[9];
    const float* self_b = (const float*)d_in[10];
    const float* msg_w = (const float*)d_in[11];
    const float* msg_b = (const float*)d_in[12];
    const float* upd_w = (const float*)d_in[13];
    const float* upd_b = (const float*)d_in[14];
    float* out = (float*)d_out;

    char* ws = (char*)d_ws;
    u16* W16 = (u16*)(ws + 0);                 // 16,777,216
    u16* S_a = (u16*)(ws + 16777216);          // 1,048,576
    u16* S_b = (u16*)(ws + 17825792);          // 1,048,576
    u16* XTs_a = (u16*)(ws + 18874368);        // 1,048,576
    u16* XTs_b = (u16*)(ws + 19922944);        // 1,048,576
    u16* atom16 = (u16*)(ws + 20971520);       // 32,768
    u16* outwT = (u16*)(ws + 21004288);        // 65,536
    u16* selfT = (u16*)(ws + 21069824);        // 98,304
    u16* msgT = (u16*)(ws + 21168128);         // 98,304
    u16* updT = (u16*)(ws + 21266432);         // 196,608
    unsigned* bar = (unsigned*)(ws + 21463040);  // 8 bytes

    hipMemsetAsync(bar, 0, 8, stream);
    geo_kernel<<<NBLK, 1024, 0, stream>>>(
        coords, Z, atom_emb, gamma, centers, rbf_w, rbf_b, out_w, out_b,
        self_w, self_b, msg_w, msg_b, upd_w,
        W16, atom16, outwT, selfT, msgT, updT, S_a, XTs_a, bar);
    mp3_kernel<<<NBLK, 512, 0, stream>>>(
        W16, selfT, msgT, updT, self_b, msg_b, upd_b,
        S_a, XTs_a, S_b, XTs_b, out, bar);
}

// Round 5
// 108.095 us; speedup vs baseline: 2.8190x; 2.8190x over previous
//
#include <hip/hip_runtime.h>
#include <hip/hip_bf16.h>

typedef unsigned short u16;
typedef __bf16 bf16x8 __attribute__((ext_vector_type(8)));
typedef float f32x4 __attribute__((ext_vector_type(4)));
typedef u16 u16x4 __attribute__((ext_vector_type(4)));

#define B_ 2
#define L_ 2048
#define D_ 128
#define KLAY 3
#define NR 16
#define NATOM 118
#define DD (D_ * D_)
#define XTN (L_ * D_)

static __device__ __forceinline__ u16 f2bf(float f) {
    union { float f; unsigned u; } v; v.f = f;
    unsigned r = v.u + 0x7FFFu + ((v.u >> 16) & 1u);
    return (u16)(r >> 16);
}
static __device__ __forceinline__ bf16x8 ld_bf8(const u16* p) {
    return *(const bf16x8*)p;
}

// ---------------- prep: weights -> bf16 [n][k] layouts ----------------
__global__ __launch_bounds__(256) void prep_kernel(
    const float* atom_emb, const float* out_w, const float* self_w,
    const float* msg_w, const float* upd_w,
    u16* atom16, u16* outwT, u16* selfT, u16* msgT, u16* updT) {
    const int T0 = NATOM * D_;
    const int T1 = D_ * 2 * D_;
    const int T2 = KLAY * DD;
    const int T3 = KLAY * DD;
    const int T4 = KLAY * 2 * DD;
    int total = T0 + T1 + T2 + T3 + T4;
    for (int t = blockIdx.x * blockDim.x + threadIdx.x; t < total;
         t += gridDim.x * blockDim.x) {
        int u = t;
        if (u < T0) { atom16[u] = f2bf(atom_emb[u]); continue; }
        u -= T0;
        if (u < T1) {
            int n = u / (2 * D_), k = u % (2 * D_);
            outwT[u] = f2bf(out_w[k * D_ + n]);
            continue;
        }
        u -= T1;
        if (u < T2) {
            int kk = u / DD, v = u % DD;
            int n = v / D_, k = v % D_;
            selfT[u] = f2bf(self_w[kk * DD + k * D_ + n]);
            continue;
        }
        u -= T2;
        if (u < T3) {
            int kk = u / DD, v = u % DD;
            int n = v / D_, k = v % D_;
            msgT[u] = f2bf(msg_w[kk * DD + k * D_ + n]);
            continue;
        }
        u -= T3;
        {
            int kk = u / (2 * DD), v = u % (2 * DD);
            int n = v / (2 * D_), k = v % (2 * D_);
            updT[u] = f2bf(upd_w[kk * 2 * DD + k * D_ + n]);
        }
    }
}

// ---------------- rbf: rbf_local via grouped-exp identity (9 trans/pair) ----------------
// exp(-g(d-c_{4q}-m*dl)^2) = base_q * u_q^m * K_m,  K_m=exp(-g(m*dl)^2)
__global__ __launch_bounds__(256) void rbf_kernel(
    const float* coords, const float* gamma_p, const float* centers,
    float* rbf_loc) {
    int w = threadIdx.x >> 6, lane = threadIdx.x & 63;
    int bi = blockIdx.x * 4 + w;  // row in [0, B*L)
    int b = bi >> 11;
    float gamma = gamma_p[0];
    float dl = centers[1] - centers[0];
    float c4[4];
#pragma unroll
    for (int g = 0; g < 4; g++) c4[g] = centers[4 * g];
    float two_gdl = 2.f * gamma * dl;
    float cx = coords[bi * 3 + 0];
    float cy = coords[bi * 3 + 1];
    float cz = coords[bi * 3 + 2];
    const float* cb = coords + (size_t)b * L_ * 3;
    float acc[4][4];
#pragma unroll
    for (int g = 0; g < 4; g++)
#pragma unroll
        for (int m = 0; m < 4; m++) acc[g][m] = 0.f;
    for (int it = 0; it < L_ / 64; it++) {
        int j = lane + 64 * it;
        float dx = cx - cb[j * 3 + 0];
        float dy = cy - cb[j * 3 + 1];
        float dz = cz - cb[j * 3 + 2];
        float sq = dx * dx + dy * dy + dz * dz;
        float d = sq > 0.f ? sqrtf(sq) : 0.f;
#pragma unroll
        for (int g = 0; g < 4; g++) {
            float x = d - c4[g];
            float base = __expf(-gamma * x * x);
            float u = __expf(fminf(two_gdl * x, 29.f));
            float p = base;
            acc[g][0] += p;
            p *= u; acc[g][1] += p;
            p *= u; acc[g][2] += p;
            p *= u; acc[g][3] += p;
        }
    }
#pragma unroll
    for (int off = 32; off > 0; off >>= 1)
#pragma unroll
        for (int g = 0; g < 4; g++)
#pragma unroll
            for (int m = 0; m < 4; m++) acc[g][m] += __shfl_xor(acc[g][m], off);
    if (lane == 0) {
#pragma unroll
        for (int m = 0; m < 4; m++) {
            float Km = __expf(-gamma * (m * dl) * (m * dl)) * (1.0f / L_);
#pragma unroll
            for (int g = 0; g < 4; g++)
                rbf_loc[(size_t)bi * NR + 4 * g + m] = acc[g][m] * Km;
        }
    }
}

// ---------------- enc_sx: encoder + layer-0 S/X (row-local) ----------------
__global__ __launch_bounds__(256) void enc_sx_kernel(
    const int* Z, const float* rbf_w, const float* rbf_b, const float* out_b,
    const float* rbf_loc, const u16* atom16, const u16* outwT,
    const u16* selfT0, const u16* msgT0, const float* self_b0, const float* msg_b0,
    u16* S16, u16* XT16) {
    int gi0 = blockIdx.x * 16;
    int b = gi0 >> 11;
    int il0 = gi0 & (L_ - 1);
    int tid = threadIdx.x;
    __shared__ __align__(16) u16 hgeo[16][136];
    __shared__ __align__(16) u16 h_lds[16][136];
    for (int e = tid; e < 16 * D_; e += 256) {
        int row = e >> 7, d = e & 127;
        int gi = gi0 + row;
        float s = rbf_b[d];
#pragma unroll
        for (int r = 0; r < NR; r++)
            s += rbf_loc[(size_t)gi * NR + r] * rbf_w[r * D_ + d];
        hgeo[row][d] = f2bf(s);
    }
    __syncthreads();
    int w = tid >> 6, lane = tid & 63;
    int rowf = lane & 15, kg = lane >> 4;
    f32x4 z = {0.f, 0.f, 0.f, 0.f};
    f32x4 acc[2] = {z, z};
    int za = Z[gi0 + rowf];
    for (int ks = 0; ks < 8; ks++) {
        int k0 = ks * 32 + kg * 8;
        bf16x8 a;
        if (k0 < 128) a = ld_bf8(atom16 + za * D_ + k0);
        else a = ld_bf8(&hgeo[rowf][k0 - 128]);
#pragma unroll
        for (int q = 0; q < 2; q++) {
            int cl = (w * 2 + q) * 16 + rowf;
            bf16x8 bb = ld_bf8(outwT + cl * (2 * D_) + k0);
            acc[q] = __builtin_amdgcn_mfma_f32_16x16x32_bf16(a, bb, acc[q], 0, 0, 0);
        }
    }
#pragma unroll
    for (int q = 0; q < 2; q++) {
        int cl = (w * 2 + q) * 16 + rowf;
        float bias = out_b[cl];
#pragma unroll
        for (int r = 0; r < 4; r++) h_lds[kg * 4 + r][cl] = f2bf(acc[q][r] + bias);
    }
    __syncthreads();
    f32x4 acc3[4] = {z, z, z, z};
    for (int ks = 0; ks < 4; ks++) {
        int k0 = ks * 32 + kg * 8;
        bf16x8 a = ld_bf8(&h_lds[rowf][k0]);
#pragma unroll
        for (int q = 0; q < 4; q++) {
            int nb = w * 4 + q;
            const u16* wp = (nb < 8) ? (selfT0 + (nb * 16 + rowf) * D_ + k0)
                                     : (msgT0 + ((nb - 8) * 16 + rowf) * D_ + k0);
            acc3[q] = __builtin_amdgcn_mfma_f32_16x16x32_bf16(a, ld_bf8(wp), acc3[q], 0, 0, 0);
        }
    }
#pragma unroll
    for (int q = 0; q < 4; q++) {
        int nb = w * 4 + q;
        if (nb < 8) {
            int cl = nb * 16 + rowf;
            float bias = self_b0[cl];
#pragma unroll
            for (int r = 0; r < 4; r++)
                S16[(size_t)(gi0 + kg * 4 + r) * D_ + cl] = f2bf(acc3[q][r] + bias);
        } else {
            int cl = (nb - 8) * 16 + rowf;
            float bias = msg_b0[cl];
            u16x4 pk;
#pragma unroll
            for (int r = 0; r < 4; r++) pk[r] = f2bf(acc3[q][r] + bias);
            int jj = il0 + kg * 4;  // 4 consecutive j, same 32-block
            *(u16x4*)(XT16 + (size_t)b * XTN + (jj >> 5) * (32 * D_) + cl * 32 + (jj & 31)) = pk;
        }
    }
}

// ---------------- mp_fused: W computed on the fly; msg GEMM + epilogue + next S/X ----------------
__global__ __launch_bounds__(512, 2) void mp_fused_kernel(
    const float* coords, const u16* XT_in, const u16* S_in,
    const u16* updT_k, const float* upd_b_k,
    const u16* selfTn, const u16* msgTn, const float* self_bn, const float* msg_bn,
    u16* S_out, u16* XT_out, float* out_f32, int last) {
    int gi0 = blockIdx.x * 16;
    int b = gi0 >> 11;
    int il0 = gi0 & (L_ - 1);
    int tid = threadIdx.x;
    int w = tid >> 6, lane = tid & 63;
    int rowf = lane & 15, kg = lane >> 4;

    __shared__ __align__(16) float red[4][16][128];  // 32 KB
    __shared__ __align__(16) float cj[L_ * 3];       // 24 KB coords of batch b
    u16* msg_lds = (u16*)&red[0][0][0];              // [16][136] bf16 alias
    u16* h_lds = (u16*)&red[1][0][0];                // [16][136] bf16 alias

    // stage coords[b] into LDS (1536 float4)
    {
        const float4* src = (const float4*)(coords + (size_t)b * L_ * 3);
        float4* dst = (float4*)cj;
#pragma unroll
        for (int i = 0; i < 3; i++) dst[tid + i * 512] = src[tid + i * 512];
    }
    __syncthreads();

    float rx = cj[(il0 + rowf) * 3 + 0];
    float ry = cj[(il0 + rowf) * 3 + 1];
    float rz = cj[(il0 + rowf) * 3 + 2];

    f32x4 z = {0.f, 0.f, 0.f, 0.f};
    f32x4 acc[8] = {z, z, z, z, z, z, z, z};
    const u16* xbase = XT_in + (size_t)b * XTN + (w * 8) * (32 * D_) + rowf * 32 + kg * 8;
#pragma unroll
    for (int s = 0; s < 8; s++) {
        int j0 = w * 256 + s * 32 + kg * 8;  // this lane's 8 j's
        const float* jc = &cj[j0 * 3];
        union { bf16x8 v; __bf16 e[8]; } wf;
#pragma unroll
        for (int e = 0; e < 8; e++) {
            float dx = rx - jc[e * 3 + 0];
            float dy = ry - jc[e * 3 + 1];
            float dz = rz - jc[e * 3 + 2];
            float sq = dx * dx + dy * dy + dz * dz;
            float d = sq > 0.f ? sqrtf(sq) : 0.f;
            wf.e[e] = (__bf16)__expf(-d);
        }
#pragma unroll
        for (int n = 0; n < 8; n++) {
            bf16x8 bb = ld_bf8(xbase + s * (32 * D_) + n * 512);
            acc[n] = __builtin_amdgcn_mfma_f32_16x16x32_bf16(wf.v, bb, acc[n], 0, 0, 0);
        }
    }
    // ---- LDS tree reduce across 8 waves ----
    auto stash = [&](int slot) {
#pragma unroll
        for (int n = 0; n < 8; n++)
#pragma unroll
            for (int r = 0; r < 4; r++) {
                int row = kg * 4 + r, col = n * 16 + rowf;
                red[slot][row][(col + 4 * row) & 127] = acc[n][r];
            }
    };
    auto grab = [&](int slot) {
#pragma unroll
        for (int n = 0; n < 8; n++)
#pragma unroll
            for (int r = 0; r < 4; r++) {
                int row = kg * 4 + r, col = n * 16 + rowf;
                acc[n][r] += red[slot][row][(col + 4 * row) & 127];
            }
    };
    if (w >= 4) stash(w - 4);
    __syncthreads();
    if (w < 4) grab(w);
    if (w == 2 || w == 3) stash(w);
    __syncthreads();
    if (w < 2) grab(w + 2);
    if (w == 1) stash(3);
    __syncthreads();
    if (w == 0) {
        grab(3);
#pragma unroll
        for (int n = 0; n < 8; n++)
#pragma unroll
            for (int r = 0; r < 4; r++)
                msg_lds[(kg * 4 + r) * 136 + n * 16 + rowf] = f2bf(acc[n][r]);
    }
    __syncthreads();
    // ---- epilogue: h' = S@U_top + msg@U_bot + bias ----
    f32x4 acc2 = z;
    int cl = w * 16 + rowf;
#pragma unroll
    for (int ks = 0; ks < 8; ks++) {
        int k0 = ks * 32 + kg * 8;
        bf16x8 av = (ks < 4) ? ld_bf8(S_in + (size_t)(gi0 + rowf) * D_ + k0)
                             : ld_bf8(msg_lds + rowf * 136 + (k0 - 128));
        acc2 = __builtin_amdgcn_mfma_f32_16x16x32_bf16(
            av, ld_bf8(updT_k + cl * 2 * D_ + k0), acc2, 0, 0, 0);
    }
    float bias = upd_b_k[cl];
    if (last) {
#pragma unroll
        for (int r = 0; r < 4; r++)
            out_f32[(size_t)(gi0 + kg * 4 + r) * D_ + cl] = acc2[r] + bias;
        return;
    }
#pragma unroll
    for (int r = 0; r < 4; r++)
        h_lds[(kg * 4 + r) * 136 + cl] = f2bf(acc2[r] + bias);
    __syncthreads();
    // ---- next-layer S/X (row-local) ----
    f32x4 a30 = z, a31 = z;
#pragma unroll
    for (int ks = 0; ks < 4; ks++) {
        int k0 = ks * 32 + kg * 8;
        bf16x8 av = ld_bf8(h_lds + rowf * 136 + k0);
        a30 = __builtin_amdgcn_mfma_f32_16x16x32_bf16(
            av, ld_bf8(selfTn + cl * D_ + k0), a30, 0, 0, 0);
        a31 = __builtin_amdgcn_mfma_f32_16x16x32_bf16(
            av, ld_bf8(msgTn + cl * D_ + k0), a31, 0, 0, 0);
    }
    float bs = self_bn[cl], bm = msg_bn[cl];
#pragma unroll
    for (int r = 0; r < 4; r++)
        S_out[(size_t)(gi0 + kg * 4 + r) * D_ + cl] = f2bf(a30[r] + bs);
    u16x4 pk;
#pragma unroll
    for (int r = 0; r < 4; r++) pk[r] = f2bf(a31[r] + bm);
    int jj = il0 + kg * 4;
    *(u16x4*)(XT_out + (size_t)b * XTN + (jj >> 5) * (32 * D_) + cl * 32 + (jj & 31)) = pk;
}

extern "C" void kernel_launch(void* const* d_in, const int* in_sizes, int n_in,
                              void* d_out, int out_size, void* d_ws, size_t ws_size,
                              hipStream_t stream) {
    const float* coords = (const float*)d_in[0];
    const int* Z = (const int*)d_in[1];
    const float* atom_emb = (const float*)d_in[2];
    const float* gamma = (const float*)d_in[3];
    const float* centers = (const float*)d_in[4];
    const float* rbf_w = (const float*)d_in[5];
    const float* rbf_b = (const float*)d_in[6];
    const float* out_w = (const float*)d_in[7];
    const float* out_b = (const float*)d_in[8];
    const float* self_w = (const float*)d_in[9];
    const float* self_b = (const float*)d_in[10];
    const float* msg_w = (const float*)d_in[11];
    const float* msg_b = (const float*)d_in[12];
    const float* upd_w = (const float*)d_in[13];
    const float* upd_b = (const float*)d_in[14];
    float* out = (float*)d_out;

    char* ws = (char*)d_ws;
    u16* S_a = (u16*)(ws + 0);              // 1,048,576
    u16* S_b = (u16*)(ws + 1048576);        // 1,048,576
    u16* XT_a = (u16*)(ws + 2097152);       // 1,048,576
    u16* XT_b = (u16*)(ws + 3145728);       // 1,048,576
    float* rbfl = (float*)(ws + 4194304);   // 262,144
    u16* atom16 = (u16*)(ws + 4456448);     // 32,768
    u16* outwT = (u16*)(ws + 4489216);      // 65,536
    u16* selfT = (u16*)(ws + 4554752);      // 98,304
    u16* msgT = (u16*)(ws + 4653056);       // 98,304
    u16* updT = (u16*)(ws + 4751360);       // 196,608

    prep_kernel<<<64, 256, 0, stream>>>(atom_emb, out_w, self_w, msg_w, upd_w,
                                        atom16, outwT, selfT, msgT, updT);
    rbf_kernel<<<(B_ * L_) / 4, 256, 0, stream>>>(coords, gamma, centers, rbfl);
    enc_sx_kernel<<<(B_ * L_) / 16, 256, 0, stream>>>(
        Z, rbf_w, rbf_b, out_b, rbfl, atom16, outwT,
        selfT, msgT, self_b, msg_b, S_a, XT_a);
    // layer 0: a -> b
    mp_fused_kernel<<<256, 512, 0, stream>>>(
        coords, XT_a, S_a, updT + 0 * 2 * DD, upd_b + 0 * D_,
        selfT + 1 * DD, msgT + 1 * DD, self_b + 1 * D_, msg_b + 1 * D_,
        S_b, XT_b, out, 0);
    // layer 1: b -> a
    mp_fused_kernel<<<256, 512, 0, stream>>>(
        coords, XT_b, S_b, updT + 1 * 2 * DD, upd_b + 1 * D_,
        selfT + 2 * DD, msgT + 2 * DD, self_b + 2 * D_, msg_b + 2 * D_,
        S_a, XT_a, out, 0);
    // layer 2 (last): a -> out
    mp_fused_kernel<<<256, 512, 0, stream>>>(
        coords, XT_a, S_a, updT + 2 * 2 * DD, upd_b + 2 * D_,
        selfT, msgT, self_b, msg_b, S_b, XT_b, out, 1);
}